// Round 6
// baseline (1180.763 us; speedup 1.0000x reference)
//
#include <hip/hip_runtime.h>
#include <math.h>

#define B_  8
#define T_  400
#define F_  256
#define D_  64
#define K_  16
#define N_  (T_*F_)        // 102400
#define TILE 256
#define NBLK (N_/TILE)     // 400
#define PSLOT 2064         // floats per partial slot: 1024 sx + 1024 sx2 + 16 cs
#define SG 8               // slot groups in reducek
#define SPG (NBLK/SG)      // 50

// ---------------- workspace layout (floats) ----------------
// 16512  pinv    8192   [b][c][k][j], c=d/4, j=d%4
// 24704  pw      8192
// 32896  pc0     128
// 33024  cs      128    \
// 33152  sx      8192    > contiguous, zeroed per iteration (sx2 = sx+8192)
// 41344  sx2     8192   /
// 49536  part    B_*NBLK*PSLOT = 6,604,800  (~26.4 MB)

// init: derived params directly from means_in with var=COV_INIT=1, pi=1/16.
// one wave per (b,k).
__global__ void initk(const float* __restrict__ means_in,
                      float* __restrict__ pinv, float* __restrict__ pw,
                      float* __restrict__ pc0) {
    int bk = blockIdx.x;          // 0..127
    int b  = bk >> 4;
    int k  = bk & 15;
    int d  = threadIdx.x;         // 0..63
    float m    = means_in[bk * D_ + d];
    const float inv0 = 1.0f / (1.0f + 1e-6f);
    int tck = ((b*16 + (d >> 2))*16 + k)*4 + (d & 3);   // [b][c][k][j]
    pinv[tck] = inv0;
    pw[tck]   = m * inv0;
    float r1 = logf(6.283185307179586f);   // log(2*pi*1.0)
    float r2 = m * m * inv0;
    #pragma unroll
    for (int off = 32; off > 0; off >>= 1) {
        r1 += __shfl_xor(r1, off);
        r2 += __shfl_xor(r2, off);
    }
    if (d == 0) pc0[bk] = logf(1.0f / K_) - 0.5f * (r1 + r2);
}

// fused M-step + param prep: cs/sx/sx2 -> pinv/pw/pc0. one wave per (b,k).
__global__ void mpk(const float* __restrict__ cs, const float* __restrict__ sx,
                    const float* __restrict__ sx2,
                    float* __restrict__ pinv, float* __restrict__ pw,
                    float* __restrict__ pc0) {
    int bk = blockIdx.x;          // 0..127
    int b  = bk >> 4;
    int k  = bk & 15;
    int d  = threadIdx.x;         // 0..63
    float csv = cs[bk];
    float sum = 0.f;
    #pragma unroll
    for (int j = 0; j < 16; ++j) sum += cs[b*K_ + j];
    int idx = bk * D_ + d;
    float sxv = sx[idx], sx2v = sx2[idx];
    float mean = sxv / (csv + 1e-7f);
    float var  = fmaf(mean*mean, csv, fmaf(-2.0f*mean, sxv, sx2v)) + 1e-6f;
    float inv  = 1.0f / (var + 1e-6f);
    int tck = ((b*16 + (d >> 2))*16 + k)*4 + (d & 3);   // [b][c][k][j]
    pinv[tck] = inv;
    pw[tck]   = mean * inv;
    float r1 = logf(6.283185307179586f * var);
    float r2 = mean * mean * inv;
    #pragma unroll
    for (int off = 32; off > 0; off >>= 1) {
        r1 += __shfl_xor(r1, off);
        r2 += __shfl_xor(r2, off);
    }
    if (d == 0) pc0[bk] = logf(csv / sum) - 0.5f * (r1 + r2);
}

// fused E-step. Tile = 256 points, 2 chunks of 128.
// Phase A (2 lanes/point, dim-halves): x from registers (prefetched), params
// from LDS, compute lik, pair-reduce, softmax; x staged to xlT as DWORDS with
// col = p ^ (d&31)  -> every LDS access spans 32 banks, 2 lanes/bank (free).
// Phase B (lane-owns-dim): wave w owns k-quad w, lane l owns dim l; both
// operands from LDS (x conflict-free, post4 broadcast); no shuffle tree.
// Chunk-1 x prefetched into registers before chunk-0 phase B (T14).
__global__ __launch_bounds__(256, 3) void estepk(
        const float* __restrict__ xg,
        const float* __restrict__ pinv, const float* __restrict__ pw,
        const float* __restrict__ pc0,
        float* __restrict__ cs, float* __restrict__ sx, float* __restrict__ sx2,
        float* __restrict__ part) {
    __shared__ float  xlT[64][128];   // 32 KB, dword, col = p ^ (row&31)
    __shared__ float4 post4[4][128];  // 8 KB;  post4[q][p] = post[4q..4q+3][p]
    __shared__ float4 ivl[256];       // 4 KB;  pinv[b] in [c][k] float4 layout
    __shared__ float4 wvl[256];       // 4 KB;  pw[b]

    const int t  = threadIdx.x;
    const int b  = blockIdx.y;
    const int n0 = blockIdx.x * TILE;
    const int l  = t & 63;
    const int w  = t >> 6;            // wave 0..3

    ivl[t] = ((const float4*)pinv)[b*256 + t];
    wvl[t] = ((const float4*)pw  )[b*256 + t];

    float c0r[16];
    #pragma unroll
    for (int k = 0; k < 16; ++k) c0r[k] = pc0[b*K_ + k];    // uniform

    // phase-A mapping: 2 lanes per point
    const int pl = w*32 + (l >> 1);   // point within chunk 0..127
    const int h  = l & 1;             // dim half

    // prefetch chunk 0 into registers (full unroll -> static indices)
    const float4* px = (const float4*)xg + ((size_t)b*N_ + n0 + pl) * 16 + 8*h;
    float4 xr[8];
    #pragma unroll
    for (int c = 0; c < 8; ++c) xr[c] = px[c];

    // phase-B accumulators: lane l = dim, wave w = k-quad
    float sa[4], s2a[4], ca[4];
    #pragma unroll
    for (int i = 0; i < 4; ++i) { sa[i] = 0.f; s2a[i] = 0.f; ca[i] = 0.f; }
    const int sxr = l & 31;           // phase-B col swizzle

    __syncthreads();                  // params staged

    #pragma unroll 1
    for (int cc = 0; cc < 2; ++cc) {
        // ---- phase A ----
        float t1[16], t2[16];
        #pragma unroll
        for (int k = 0; k < 16; ++k) { t1[k] = 0.f; t2[k] = 0.f; }

        #pragma unroll
        for (int c = 0; c < 8; ++c) {
            float4 xv = xr[c];
            const int dd = 4*(8*h + c);          // dim of xv.x
            xlT[dd+0][pl ^ ((dd+0)&31)] = xv.x;  // 32 banks, 2-way (free)
            xlT[dd+1][pl ^ ((dd+1)&31)] = xv.y;
            xlT[dd+2][pl ^ ((dd+2)&31)] = xv.z;
            xlT[dd+3][pl ^ ((dd+3)&31)] = xv.w;
            float4 qv;
            qv.x = xv.x*xv.x; qv.y = xv.y*xv.y; qv.z = xv.z*xv.z; qv.w = xv.w*xv.w;
            const float4* ivc = &ivl[(8*h + c)*16];
            const float4* wvc = &wvl[(8*h + c)*16];
            #pragma unroll
            for (int k = 0; k < 16; ++k) {
                float4 iv = ivc[k];              // 2 addrs/wave -> 2-way (free)
                float4 wv = wvc[k];
                t2[k] = fmaf(qv.x, iv.x, fmaf(qv.y, iv.y, fmaf(qv.z, iv.z, fmaf(qv.w, iv.w, t2[k]))));
                t1[k] = fmaf(xv.x, wv.x, fmaf(xv.y, wv.y, fmaf(xv.z, wv.z, fmaf(xv.w, wv.w, t1[k]))));
            }
        }

        // pair-reduce the two dim-halves (lanes 2p, 2p+1)
        #pragma unroll
        for (int k = 0; k < 16; ++k) {
            t1[k] += __shfl_xor(t1[k], 1);
            t2[k] += __shfl_xor(t2[k], 1);
        }

        // softmax over K=16 (redundant in the lane pair); STATIC indices only
        float po[16]; float mx = -1e30f;
        #pragma unroll
        for (int k = 0; k < 16; ++k) { po[k] = c0r[k] + t1[k] - 0.5f*t2[k]; mx = fmaxf(mx, po[k]); }
        float s = 0.f;
        #pragma unroll
        for (int k = 0; k < 16; ++k) { po[k] = __expf(po[k] - mx); s += po[k]; }
        float is = 1.0f / s;
        if (h == 0) {
            post4[0][pl] = make_float4(po[0]*is,  po[1]*is,  po[2]*is,  po[3]*is);
            post4[1][pl] = make_float4(po[4]*is,  po[5]*is,  po[6]*is,  po[7]*is);
        } else {
            post4[2][pl] = make_float4(po[8]*is,  po[9]*is,  po[10]*is, po[11]*is);
            post4[3][pl] = make_float4(po[12]*is, po[13]*is, po[14]*is, po[15]*is);
        }

        // T14: issue chunk-1 global loads now; they fly under barrier+phase B
        if (cc == 0) {
            #pragma unroll
            for (int c = 0; c < 8; ++c) xr[c] = px[128*16 + c];
        }
        __syncthreads();                 // xlT/post4 ready

        // ---- phase B: all LDS, conflict-free ----
        #pragma unroll 4
        for (int p = 0; p < 128; ++p) {
            float  xv = xlT[l][p ^ sxr];  // 32 banks, 2-way (free)
            float4 pv = post4[w][p];      // wave-uniform broadcast
            float  qv = xv * xv;
            sa[0]  = fmaf(pv.x, xv, sa[0]);
            sa[1]  = fmaf(pv.y, xv, sa[1]);
            sa[2]  = fmaf(pv.z, xv, sa[2]);
            sa[3]  = fmaf(pv.w, xv, sa[3]);
            s2a[0] = fmaf(pv.x, qv, s2a[0]);
            s2a[1] = fmaf(pv.y, qv, s2a[1]);
            s2a[2] = fmaf(pv.z, qv, s2a[2]);
            s2a[3] = fmaf(pv.w, qv, s2a[3]);
            ca[0] += pv.x; ca[1] += pv.y; ca[2] += pv.z; ca[3] += pv.w;
        }
        if (cc == 0) __syncthreads();    // before chunk 1 overwrites xlT
    }

    if (part) {
        // per-block partial slot; every (k,d) owned by exactly one lane ->
        // fully coalesced dword stores, all 64 lanes active, no atomics
        float* pp = part + ((size_t)(b*NBLK + blockIdx.x)) * PSLOT;
        #pragma unroll
        for (int i = 0; i < 4; ++i) {
            pp[(4*w + i)*64 + l]        = sa[i];
            pp[1024 + (4*w + i)*64 + l] = s2a[i];
        }
        if (l == 0) {
            #pragma unroll
            for (int i = 0; i < 4; ++i) pp[2048 + 4*w + i] = ca[i];
        }
    } else {
        #pragma unroll
        for (int i = 0; i < 4; ++i) {
            atomicAdd(&sx [(size_t)(b*K_ + 4*w + i)*D_ + l], sa[i]);
            atomicAdd(&sx2[(size_t)(b*K_ + 4*w + i)*D_ + l], s2a[i]);
        }
        if (l == 0) {
            #pragma unroll
            for (int i = 0; i < 4; ++i) atomicAdd(&cs[b*K_ + 4*w + i], ca[i]);
        }
    }
}

// fold NBLK partial slots into cs/sx/sx2. grid (65, SG); each block sums SPG
// slots; 8 atomic folds per output element total.
__global__ __launch_bounds__(256) void reducek(const float* __restrict__ part,
                                               float* __restrict__ cs,
                                               float* __restrict__ sx) {
    const int idx = blockIdx.x * 256 + threadIdx.x;
    const int s0  = blockIdx.y * SPG;
    if (idx < B_*2048) {
        const int b = idx >> 11, off = idx & 2047;
        const float* pp = part + ((size_t)(b*NBLK + s0)) * PSLOT + off;
        float sum = 0.f;
        #pragma unroll 10
        for (int s = 0; s < SPG; ++s) sum += pp[(size_t)s * PSLOT];
        float* dst = (off < 1024) ? (sx + b*1024 + off)
                                  : (sx + 8192 + b*1024 + (off - 1024));   // sx2
        atomicAdd(dst, sum);
    } else if (idx < B_*2048 + B_*K_) {
        const int c = idx - B_*2048;
        const int b = c >> 4, k = c & 15;
        const float* pp = part + ((size_t)(b*NBLK + s0)) * PSLOT + 2048 + k;
        float sum = 0.f;
        #pragma unroll 10
        for (int s = 0; s < SPG; ++s) sum += pp[(size_t)s * PSLOT];
        atomicAdd(&cs[b*16 + k], sum);
    }
}

// final lik -> sigmoid(scale*lik + bias) -> out[b][n][k]; one point per thread
__global__ __launch_bounds__(256, 6) void finalk(
        const float* __restrict__ xg,
        const float* __restrict__ pinv, const float* __restrict__ pw,
        const float* __restrict__ pc0,
        const float* __restrict__ scale, const float* __restrict__ bias,
        float* __restrict__ out) {
    const int t  = threadIdx.x;
    const int b  = blockIdx.y;
    const int n0 = blockIdx.x * TILE;

    const float4* iv4 = (const float4*)(pinv + (size_t)(b*K_*D_));
    const float4* wv4 = (const float4*)(pw   + (size_t)(b*K_*D_));

    float c0r[16];
    #pragma unroll
    for (int k = 0; k < 16; ++k) c0r[k] = pc0[b*K_ + k];

    const float4* px = (const float4*)(xg + ((size_t)b*N_ + n0 + t) * D_);

    float t1[16], t2[16];
    #pragma unroll
    for (int k = 0; k < 16; ++k) { t1[k] = 0.f; t2[k] = 0.f; }

    #pragma unroll 4
    for (int c = 0; c < D_/4; ++c) {
        float4 xv = px[c];
        float4 qv;
        qv.x = xv.x*xv.x; qv.y = xv.y*xv.y; qv.z = xv.z*xv.z; qv.w = xv.w*xv.w;
        const float4* ivc = iv4 + c*16;
        const float4* wvc = wv4 + c*16;
        #pragma unroll
        for (int k = 0; k < 16; ++k) {
            float4 iv = ivc[k];
            float4 wv = wvc[k];
            t2[k] = fmaf(qv.x, iv.x, fmaf(qv.y, iv.y, fmaf(qv.z, iv.z, fmaf(qv.w, iv.w, t2[k]))));
            t1[k] = fmaf(xv.x, wv.x, fmaf(xv.y, wv.y, fmaf(xv.z, wv.z, fmaf(xv.w, wv.w, t1[k]))));
        }
    }

    const float sc = scale[0], bi = bias[0];
    float4* op = (float4*)(out + ((size_t)b*N_ + n0 + t) * (size_t)K_);
    #pragma unroll
    for (int q = 0; q < 4; ++q) {
        float4 o;
        float z0 = (c0r[4*q+0] + t1[4*q+0] - 0.5f*t2[4*q+0]) * sc + bi;
        float z1 = (c0r[4*q+1] + t1[4*q+1] - 0.5f*t2[4*q+1]) * sc + bi;
        float z2 = (c0r[4*q+2] + t1[4*q+2] - 0.5f*t2[4*q+2]) * sc + bi;
        float z3 = (c0r[4*q+3] + t1[4*q+3] - 0.5f*t2[4*q+3]) * sc + bi;
        o.x = 1.0f / (1.0f + __expf(-z0));
        o.y = 1.0f / (1.0f + __expf(-z1));
        o.z = 1.0f / (1.0f + __expf(-z2));
        o.w = 1.0f / (1.0f + __expf(-z3));
        op[q] = o;
    }
}

extern "C" void kernel_launch(void* const* d_in, const int* in_sizes, int n_in,
                              void* d_out, int out_size, void* d_ws, size_t ws_size,
                              hipStream_t stream) {
    const float* xg       = (const float*)d_in[0];
    const float* means_in = (const float*)d_in[1];
    const float* scale    = (const float*)d_in[2];
    const float* bias     = (const float*)d_in[3];
    float* out = (float*)d_out;

    float* ws      = (float*)d_ws;
    float* pinv    = ws + 16512;
    float* pw      = ws + 24704;
    float* pc0     = ws + 32896;
    float* cs      = ws + 33024;
    float* sx      = ws + 33152;
    // sx2 = sx + 8192 (contiguous; reducek relies on this)
    float* sx2     = ws + 41344;
    float* part    = ws + 49536;

    const size_t need_floats = (size_t)49536 + (size_t)B_ * NBLK * PSLOT;  // ~26.6 MB
    if (ws_size < need_floats * sizeof(float)) part = nullptr;

    initk<<<dim3(B_*K_), dim3(64), 0, stream>>>(means_in, pinv, pw, pc0);

    for (int it = 0; it < 5; ++it) {
        hipMemsetAsync(cs, 0, (size_t)(128 + 8192 + 8192) * sizeof(float), stream);
        estepk<<<dim3(NBLK, B_), dim3(256), 0, stream>>>(xg, pinv, pw, pc0, cs, sx, sx2, part);
        if (part)
            reducek<<<dim3(65, SG), dim3(256), 0, stream>>>(part, cs, sx);
        mpk<<<dim3(B_*K_), dim3(64), 0, stream>>>(cs, sx, sx2, pinv, pw, pc0);
    }
    finalk<<<dim3(NBLK, B_), dim3(256), 0, stream>>>(xg, pinv, pw, pc0, scale, bias, out);
}